// Round 2
// baseline (1424.493 us; speedup 1.0000x reference)
//
#include <hip/hip_runtime.h>

#define HID    64
#define TSTEPS 256
#define BATCH  2048

typedef float v2f __attribute__((ext_vector_type(2)));
typedef float v4f __attribute__((ext_vector_type(4)));

// tanh(x) = 1 - 2/(exp2(2*log2(e)*x) + 1); exact at saturation
__device__ __forceinline__ float fast_tanh(float x) {
    float e = __builtin_amdgcn_exp2f(x * 2.8853900817779268f);
    float r = __builtin_amdgcn_rcpf(e + 1.0f);
    return fmaf(-2.0f, r, 1.0f);
}

__global__ __launch_bounds__(256, 2) void hnn_rk4_kernel(
        const float* __restrict__ tarr,
        const float* __restrict__ x0,
        const float* __restrict__ W1,
        const float* __restrict__ b1,
        const float* __restrict__ W2,
        const float* __restrict__ b2,
        const float* __restrict__ W3,
        float* __restrict__ out)
{
    const int lane = threadIdx.x & 63;
    const int wid  = threadIdx.x >> 6;
    const int b    = blockIdx.x * 4 + wid;    // one wave per batch element

    // per-wave 64-float broadcast buffer (h1, then g2); 16B-aligned for b128 reads
    __shared__ v4f bc[4][16];
    float* bcf = (float*)&bc[wid][0];

    const float dt  = tarr[1] - tarr[0];
    const float hdt = 0.5f * dt;
    const float sdt = dt * (1.0f / 6.0f);

    // lane i owns hidden unit i
    const float w1a = W1[2 * lane + 0];
    const float w1b = W1[2 * lane + 1];
    const float b1i = b1[lane];
    const float b2i = b2[lane];
    const float w3i = W3[lane];

    // W2 row i (pairs, for forward) and column i (pairs, for backward) in VGPRs
    v2f w2r[32], w2c[32];
#pragma unroll
    for (int k = 0; k < 32; ++k) {
        w2r[k] = *(const v2f*)(W2 + lane * HID + 2 * k);
        v2f c;
        c.x = W2[(2 * k + 0) * HID + lane];
        c.y = W2[(2 * k + 1) * HID + lane];
        w2c[k] = c;
    }

    float q = x0[2 * b + 0];
    float p = x0[2 * b + 1];

    if (lane == 0) {
        out[2 * b + 0] = q;
        out[2 * b + 1] = p;
    }

    auto dynamics = [&](float xq, float xp, float& kq, float& kp) {
        // ---- forward layer 1 (per-lane scalar) ----
        const float h1 = fast_tanh(fmaf(w1a, xq, fmaf(w1b, xp, b1i)));

        // ---- broadcast h1 via LDS (write own slot, uniform b128 reads) ----
        bcf[lane] = h1;
        v2f accA; accA.x = b2i; accA.y = 0.0f;
        v2f accB; accB.x = 0.0f; accB.y = 0.0f;
#pragma unroll
        for (int qd = 0; qd < 16; ++qd) {
            v4f h = bc[wid][qd];                 // uniform address -> broadcast
            accA = __builtin_elementwise_fma(h.xy, w2r[2 * qd + 0], accA);
            accB = __builtin_elementwise_fma(h.zw, w2r[2 * qd + 1], accB);
        }
        const float h2 = fast_tanh((accA.x + accB.x) + (accA.y + accB.y));
        const float g2 = w3i * fmaf(-h2, h2, 1.0f);

        // ---- broadcast g2, backward matvec u = W2^T g2 ----
        bcf[lane] = g2;
        v2f accC; accC.x = 0.0f; accC.y = 0.0f;
        v2f accD; accD.x = 0.0f; accD.y = 0.0f;
#pragma unroll
        for (int qd = 0; qd < 16; ++qd) {
            v4f g = bc[wid][qd];
            accC = __builtin_elementwise_fma(g.xy, w2c[2 * qd + 0], accC);
            accD = __builtin_elementwise_fma(g.zw, w2c[2 * qd + 1], accD);
        }
        const float u  = (accC.x + accD.x) + (accC.y + accD.y);
        const float g1 = u * fmaf(-h1, h1, 1.0f);

        // ---- dHdx reduce across lanes ----
        float s0 = g1 * w1a;
        float s1 = g1 * w1b;
#pragma unroll
        for (int m = 1; m < 64; m <<= 1) {
            s0 += __shfl_xor(s0, m, 64);
            s1 += __shfl_xor(s1, m, 64);
        }
        kq = s1;      //  dH/dp
        kp = -s0;     // -dH/dq
    };

#pragma unroll 1
    for (int s = 0; s < TSTEPS - 1; ++s) {
        float kq1, kp1, kq2, kp2, kq3, kp3, kq4, kp4;
        dynamics(q, p, kq1, kp1);
        dynamics(fmaf(hdt, kq1, q), fmaf(hdt, kp1, p), kq2, kp2);
        dynamics(fmaf(hdt, kq2, q), fmaf(hdt, kp2, p), kq3, kp3);
        dynamics(fmaf(dt,  kq3, q), fmaf(dt,  kp3, p), kq4, kp4);
        q = fmaf(sdt, kq1 + 2.f * kq2 + 2.f * kq3 + kq4, q);
        p = fmaf(sdt, kp1 + 2.f * kp2 + 2.f * kp3 + kp4, p);
        if (lane == 0) {
            out[(s + 1) * (BATCH * 2) + 2 * b + 0] = q;
            out[(s + 1) * (BATCH * 2) + 2 * b + 1] = p;
        }
    }
}

extern "C" void kernel_launch(void* const* d_in, const int* in_sizes, int n_in,
                              void* d_out, int out_size, void* d_ws, size_t ws_size,
                              hipStream_t stream) {
    const float* t  = (const float*)d_in[0];
    const float* x0 = (const float*)d_in[1];
    const float* W1 = (const float*)d_in[2];
    const float* b1 = (const float*)d_in[3];
    const float* W2 = (const float*)d_in[4];
    const float* b2 = (const float*)d_in[5];
    const float* W3 = (const float*)d_in[6];
    // d_in[7] = b3: additive constant in H, cancels in dH/dx — unused.

    hnn_rk4_kernel<<<dim3(BATCH / 4), dim3(256), 0, stream>>>(
        t, x0, W1, b1, W2, b2, W3, (float*)d_out);
}

// Round 3
// 995.226 us; speedup vs baseline: 1.4313x; 1.4313x over previous
//
#include <hip/hip_runtime.h>

#define HID    64
#define TSTEPS 256
#define BATCH  2048

// tanh(x) = 1 - 2/(exp2(2*log2(e)*x) + 1); exact at saturation
__device__ __forceinline__ float fast_tanh(float x) {
    float e = __builtin_amdgcn_exp2f(x * 2.8853900817779268f);
    float r = __builtin_amdgcn_rcpf(e + 1.0f);
    return fmaf(-2.0f, r, 1.0f);
}

// xor-butterfly exchange: lanes within 32-lane halves via ds_swizzle (imm pattern,
// no address register); m=32 via __shfl_xor (ds_bpermute)
template <int M>
__device__ __forceinline__ float shxf(float v) {
    if constexpr (M < 32) {
        return __int_as_float(__builtin_amdgcn_ds_swizzle(
            __float_as_int(v), (M << 10) | 0x1F));   // BitMode: xor=M, or=0, and=0x1F
    } else {
        return __shfl_xor(v, 32, 64);
    }
}

__device__ __forceinline__ float bperm(int addr, float v) {
    return __int_as_float(__builtin_amdgcn_ds_bpermute(addr, __float_as_int(v)));
}

__global__ __launch_bounds__(256, 2) void hnn_rk4_kernel(
        const float* __restrict__ tarr,
        const float* __restrict__ x0,
        const float* __restrict__ W1,
        const float* __restrict__ b1,
        const float* __restrict__ W2,
        const float* __restrict__ b2,
        const float* __restrict__ W3,
        float* __restrict__ out)
{
    const int lane = threadIdx.x & 63;
    const int wid  = threadIdx.x >> 6;
    const int b    = blockIdx.x * 4 + wid;     // one wave per batch element

    // 8x8 lane grid: lane = 8*r + c
    const int r0 = (lane >> 3) << 3;           // 8*r : my output group base
    const int c0 = (lane & 7) << 3;            // 8*c : my input group base

    const float dt  = tarr[1] - tarr[0];
    const float hdt = 0.5f * dt;
    const float sdt = dt * (1.0f / 6.0f);

    // per-unit params (unit index = lane)
    const float w1a = W1[2 * lane + 0];
    const float w1b = W1[2 * lane + 1];
    const float b1i = b1[lane];
    const float b2i = b2[lane];
    const float w3i = W3[lane];

    // broadcast source addresses (loop-invariant): lanes c0..c0+7
    int ba[8];
#pragma unroll
    for (int t = 0; t < 8; ++t) ba[t] = (c0 + t) * 4;

    // weight blocks: forward wf[o][t] = W2[r0+o][c0+t]; backward wb[o][t] = W2[c0+t][r0+o]
    float wf[64], wb[64];
#pragma unroll
    for (int o = 0; o < 8; ++o) {
#pragma unroll
        for (int t = 0; t < 8; ++t) {
            wf[o * 8 + t] = W2[(r0 + o) * HID + c0 + t];
            wb[o * 8 + t] = W2[(c0 + t) * HID + r0 + o];
        }
    }

    const bool s1b = lane & 1, s2b = lane & 2, s4b = lane & 4;

    // 3-stage recursive-halving over the 8-lane row; lane (r,c) ends with
    // the full sum for output index c (i.e. unit 8r+c == this lane).
    auto reduce8 = [&](float* f) -> float {
        float g[4], h[2];
#pragma unroll
        for (int k = 0; k < 4; ++k) {
            float keep = s1b ? f[2 * k + 1] : f[2 * k];
            float send = s1b ? f[2 * k]     : f[2 * k + 1];
            g[k] = keep + shxf<1>(send);
        }
#pragma unroll
        for (int j = 0; j < 2; ++j) {
            float keep = s2b ? g[2 * j + 1] : g[2 * j];
            float send = s2b ? g[2 * j]     : g[2 * j + 1];
            h[j] = keep + shxf<2>(send);
        }
        float keep = s4b ? h[1] : h[0];
        float send = s4b ? h[0] : h[1];
        return keep + shxf<4>(send);
    };

    float q = x0[2 * b + 0];
    float p = x0[2 * b + 1];

    if (lane == 0) {
        out[2 * b + 0] = q;
        out[2 * b + 1] = p;
    }

    auto dynamics = [&](float xq, float xp, float& kq, float& kp) {
        // layer 1 (unit = lane)
        const float h1 = fast_tanh(fmaf(w1a, xq, fmaf(w1b, xp, b1i)));

        // broadcast h1[c0..c0+7] into registers (8 bpermute, precomputed addrs)
        float hb[8];
#pragma unroll
        for (int t = 0; t < 8; ++t) hb[t] = bperm(ba[t], h1);

        // forward partials: f[o] = sum_t wf[o][t] * hb[t]
        float f[8];
#pragma unroll
        for (int o = 0; o < 8; ++o) {
            float a = hb[0] * wf[o * 8 + 0];
            float c = hb[1] * wf[o * 8 + 1];
#pragma unroll
            for (int t = 2; t < 8; t += 2) {
                a = fmaf(hb[t],     wf[o * 8 + t],     a);
                c = fmaf(hb[t + 1], wf[o * 8 + t + 1], c);
            }
            f[o] = a + c;
        }
        const float pre2 = reduce8(f) + b2i;
        const float h2   = fast_tanh(pre2);
        const float g2   = w3i * fmaf(-h2, h2, 1.0f);

        // broadcast g2[c0..c0+7]; backward partials with transposed block
        float gb[8];
#pragma unroll
        for (int t = 0; t < 8; ++t) gb[t] = bperm(ba[t], g2);

        float fb[8];
#pragma unroll
        for (int o = 0; o < 8; ++o) {
            float a = gb[0] * wb[o * 8 + 0];
            float c = gb[1] * wb[o * 8 + 1];
#pragma unroll
            for (int t = 2; t < 8; t += 2) {
                a = fmaf(gb[t],     wb[o * 8 + t],     a);
                c = fmaf(gb[t + 1], wb[o * 8 + t + 1], c);
            }
            fb[o] = a + c;
        }
        const float u  = reduce8(fb);
        const float g1 = u * fmaf(-h1, h1, 1.0f);

        // dHdx = W1^T g1 : full-wave butterfly (all lanes end with both sums)
        float s0 = g1 * w1a;
        float s1 = g1 * w1b;
        s0 += shxf<1>(s0);   s1 += shxf<1>(s1);
        s0 += shxf<2>(s0);   s1 += shxf<2>(s1);
        s0 += shxf<4>(s0);   s1 += shxf<4>(s1);
        s0 += shxf<8>(s0);   s1 += shxf<8>(s1);
        s0 += shxf<16>(s0);  s1 += shxf<16>(s1);
        s0 += shxf<32>(s0);  s1 += shxf<32>(s1);
        kq = s1;      //  dH/dp
        kp = -s0;     // -dH/dq
    };

#pragma unroll 1
    for (int s = 0; s < TSTEPS - 1; ++s) {
        float kq1, kp1, kq2, kp2, kq3, kp3, kq4, kp4;
        dynamics(q, p, kq1, kp1);
        dynamics(fmaf(hdt, kq1, q), fmaf(hdt, kp1, p), kq2, kp2);
        dynamics(fmaf(hdt, kq2, q), fmaf(hdt, kp2, p), kq3, kp3);
        dynamics(fmaf(dt,  kq3, q), fmaf(dt,  kp3, p), kq4, kp4);
        q = fmaf(sdt, kq1 + 2.f * kq2 + 2.f * kq3 + kq4, q);
        p = fmaf(sdt, kp1 + 2.f * kp2 + 2.f * kp3 + kp4, p);
        if (lane == 0) {
            out[(s + 1) * (BATCH * 2) + 2 * b + 0] = q;
            out[(s + 1) * (BATCH * 2) + 2 * b + 1] = p;
        }
    }
}

extern "C" void kernel_launch(void* const* d_in, const int* in_sizes, int n_in,
                              void* d_out, int out_size, void* d_ws, size_t ws_size,
                              hipStream_t stream) {
    const float* t  = (const float*)d_in[0];
    const float* x0 = (const float*)d_in[1];
    const float* W1 = (const float*)d_in[2];
    const float* b1 = (const float*)d_in[3];
    const float* W2 = (const float*)d_in[4];
    const float* b2 = (const float*)d_in[5];
    const float* W3 = (const float*)d_in[6];
    // d_in[7] = b3: additive constant in H, cancels in dH/dx — unused.

    hnn_rk4_kernel<<<dim3(BATCH / 4), dim3(256), 0, stream>>>(
        t, x0, W1, b1, W2, b2, W3, (float*)d_out);
}

// Round 4
// 830.104 us; speedup vs baseline: 1.7160x; 1.1989x over previous
//
#include <hip/hip_runtime.h>

#define HID    64
#define TSTEPS 256
#define BATCH  2048

typedef float v2f __attribute__((ext_vector_type(2)));

// tanh(x) = 1 - 2/(exp2(2*log2(e)*x) + 1); exact at saturation
__device__ __forceinline__ float fast_tanh(float x) {
    float e = __builtin_amdgcn_exp2f(x * 2.8853900817779268f);
    float r = __builtin_amdgcn_rcpf(e + 1.0f);
    return fmaf(-2.0f, r, 1.0f);
}

// xor-exchange within 32-lane halves, imm pattern (BitMode: xor=M, and=0x1F)
template <int M>
__device__ __forceinline__ float swz(float v) {
    return __int_as_float(__builtin_amdgcn_ds_swizzle(
        __float_as_int(v), (M << 10) | 0x1F));
}
template <int M>
__device__ __forceinline__ v2f swz2(v2f v) {
    v2f r; r.x = swz<M>(v.x); r.y = swz<M>(v.y); return r;
}

// DPP quad_perm exchange (pure VALU): 0xB1 = lane^1, 0x4E = lane^2
template <int CTRL>
__device__ __forceinline__ float dppf(float x) {
    int xi = __float_as_int(x);
    return __int_as_float(__builtin_amdgcn_update_dpp(xi, xi, CTRL, 0xF, 0xF, false));
}
template <int CTRL>
__device__ __forceinline__ v2f dpp2(v2f v) {
    v2f r; r.x = dppf<CTRL>(v.x); r.y = dppf<CTRL>(v.y); return r;
}

__device__ __forceinline__ float bperm(int addr, float v) {
    return __int_as_float(__builtin_amdgcn_ds_bpermute(addr, __float_as_int(v)));
}

__global__ __launch_bounds__(256, 2) void hnn_rk4_kernel(
        const float* __restrict__ tarr,
        const float* __restrict__ x0,
        const float* __restrict__ W1,
        const float* __restrict__ b1,
        const float* __restrict__ W2,
        const float* __restrict__ b2,
        const float* __restrict__ W3,
        float* __restrict__ out)
{
    const int lane = threadIdx.x & 63;
    const int wid  = threadIdx.x >> 6;
    const int b    = blockIdx.x * 4 + wid;     // one wave per batch element

    // 8x8 lane grid: lane = 8*r + c; lane owns W2 block rows r0..r0+7 x cols c0..c0+7
    const int r0 = (lane >> 3) << 3;
    const int c0 = (lane & 7) << 3;

    const float dt  = tarr[1] - tarr[0];
    const float hdt = 0.5f * dt;
    const float sdt = dt * (1.0f / 6.0f);

    // per-unit params (unit index = lane)
    v2f   w1v = *(const v2f*)(W1 + 2 * lane);   // (W1[i,0], W1[i,1])
    float b1i = b1[lane];
    float b2i = b2[lane];
    float w3i = W3[lane];

    // broadcast addresses: h1/g2 value of unit c0+t lives on lane c0+t
    int ba[8];
#pragma unroll
    for (int t = 0; t < 8; ++t) ba[t] = (c0 + t) * 4;
    int a32 = (lane ^ 32) * 4;

    // weight pairs, paired over OUTPUT index (r0+2m, r0+2m+1):
    //   wfT[t*4+m] = (W2[r0+2m][c0+t],  W2[r0+2m+1][c0+t])   forward
    //   wbT[t*4+m] = (W2[c0+t][r0+2m],  W2[c0+t][r0+2m+1])   backward (contiguous)
    v2f wfT[32], wbT[32];
#pragma unroll
    for (int t = 0; t < 8; ++t) {
#pragma unroll
        for (int m = 0; m < 4; ++m) {
            v2f f;
            f.x = W2[(r0 + 2 * m)     * HID + c0 + t];
            f.y = W2[(r0 + 2 * m + 1) * HID + c0 + t];
            wfT[t * 4 + m] = f;
            wbT[t * 4 + m] = *(const v2f*)(W2 + (c0 + t) * HID + r0 + 2 * m);
        }
    }

    // Pin everything in architectural VGPRs: asm results can't be rematerialized,
    // so the compiler cannot sink these loads into the time loop (R3: 167MB of
    // in-loop reloads) or round-trip them through AGPRs.
#pragma unroll
    for (int k = 0; k < 32; ++k) {
        asm volatile("" : "+v"(wfT[k]), "+v"(wbT[k]));
    }
#pragma unroll
    for (int t = 0; t < 8; ++t) asm volatile("" : "+v"(ba[t]));
    asm volatile("" : "+v"(w1v), "+v"(b1i), "+v"(b2i), "+v"(w3i), "+v"(a32));

    const bool s1b = lane & 1, s2b = lane & 2, s4b = lane & 4;

    // Reduce 4 output-pairs across the 8-lane row (bits 0..2 of lane), halving in
    // bit order (2, 4, 1): lane (r,c) ends with the complete sum for unit 8r+c.
    auto reduce_pairs = [&](v2f P0, v2f P1, v2f P2, v2f P3) -> float {
        v2f kA0 = s2b ? P1 : P0,  sA0 = s2b ? P0 : P1;
        v2f kA1 = s2b ? P3 : P2,  sA1 = s2b ? P2 : P3;
        v2f g0 = kA0 + dpp2<0x4E>(sA0);          // xor2 via quad_perm [2,3,0,1]
        v2f g1 = kA1 + dpp2<0x4E>(sA1);
        v2f kB = s4b ? g1 : g0,   sB = s4b ? g0 : g1;
        v2f h  = kB + swz2<4>(sB);               // xor4 via ds_swizzle
        v2f vf = h + dpp2<0xB1>(h);              // xor1 via quad_perm [1,0,3,2]
        return s1b ? vf.y : vf.x;
    };

    float q = x0[2 * b + 0];
    float p = x0[2 * b + 1];

    if (lane == 0) {
        out[2 * b + 0] = q;
        out[2 * b + 1] = p;
    }

    auto dynamics = [&](float xq, float xp, float& kq, float& kp) {
        // layer 1 (unit = lane)
        const float h1 = fast_tanh(fmaf(w1v.x, xq, fmaf(w1v.y, xp, b1i)));

        // broadcast h1[c0..c0+7] (precomputed addrs, zero per-eval addr VALU)
        float hb[8];
#pragma unroll
        for (int t = 0; t < 8; ++t) hb[t] = bperm(ba[t], h1);

        // forward partial pairs: P[m] = sum_t wfT[t][m] * h1[c0+t]   (pk_fma)
        v2f P0 = {0.f, 0.f}, P1 = {0.f, 0.f}, P2 = {0.f, 0.f}, P3 = {0.f, 0.f};
#pragma unroll
        for (int t = 0; t < 8; ++t) {
            v2f hh; hh.x = hb[t]; hh.y = hb[t];
            P0 = __builtin_elementwise_fma(wfT[t * 4 + 0], hh, P0);
            P1 = __builtin_elementwise_fma(wfT[t * 4 + 1], hh, P1);
            P2 = __builtin_elementwise_fma(wfT[t * 4 + 2], hh, P2);
            P3 = __builtin_elementwise_fma(wfT[t * 4 + 3], hh, P3);
        }
        const float pre2 = reduce_pairs(P0, P1, P2, P3) + b2i;
        const float h2   = fast_tanh(pre2);
        const float g2   = w3i * fmaf(-h2, h2, 1.0f);

        // broadcast g2[c0..c0+7]; backward partial pairs with transposed block
        float gb[8];
#pragma unroll
        for (int t = 0; t < 8; ++t) gb[t] = bperm(ba[t], g2);

        v2f Q0 = {0.f, 0.f}, Q1 = {0.f, 0.f}, Q2 = {0.f, 0.f}, Q3 = {0.f, 0.f};
#pragma unroll
        for (int t = 0; t < 8; ++t) {
            v2f gg; gg.x = gb[t]; gg.y = gb[t];
            Q0 = __builtin_elementwise_fma(wbT[t * 4 + 0], gg, Q0);
            Q1 = __builtin_elementwise_fma(wbT[t * 4 + 1], gg, Q1);
            Q2 = __builtin_elementwise_fma(wbT[t * 4 + 2], gg, Q2);
            Q3 = __builtin_elementwise_fma(wbT[t * 4 + 3], gg, Q3);
        }
        const float u  = reduce_pairs(Q0, Q1, Q2, Q3);
        const float g1 = u * fmaf(-h1, h1, 1.0f);

        // dHdx = W1^T g1 : full-wave butterfly on the (dH/dq, dH/dp) pair
        v2f gv; gv.x = g1; gv.y = g1;
        v2f sv = w1v * gv;
        sv = sv + dpp2<0xB1>(sv);                // xor1  (DPP)
        sv = sv + dpp2<0x4E>(sv);                // xor2  (DPP)
        sv = sv + swz2<4>(sv);                   // xor4
        sv = sv + swz2<8>(sv);                   // xor8
        sv = sv + swz2<16>(sv);                  // xor16
        v2f sw; sw.x = bperm(a32, sv.x); sw.y = bperm(a32, sv.y);
        sv = sv + sw;                            // xor32 (bpermute, pinned addr)
        kq = sv.y;      //  dH/dp
        kp = -sv.x;     // -dH/dq
    };

#pragma unroll 1
    for (int s = 0; s < TSTEPS - 1; ++s) {
        float kq1, kp1, kq2, kp2, kq3, kp3, kq4, kp4;
        dynamics(q, p, kq1, kp1);
        dynamics(fmaf(hdt, kq1, q), fmaf(hdt, kp1, p), kq2, kp2);
        dynamics(fmaf(hdt, kq2, q), fmaf(hdt, kp2, p), kq3, kp3);
        dynamics(fmaf(dt,  kq3, q), fmaf(dt,  kp3, p), kq4, kp4);
        q = fmaf(sdt, kq1 + 2.f * kq2 + 2.f * kq3 + kq4, q);
        p = fmaf(sdt, kp1 + 2.f * kp2 + 2.f * kp3 + kp4, p);
        if (lane == 0) {
            out[(s + 1) * (BATCH * 2) + 2 * b + 0] = q;
            out[(s + 1) * (BATCH * 2) + 2 * b + 1] = p;
        }
    }
}

extern "C" void kernel_launch(void* const* d_in, const int* in_sizes, int n_in,
                              void* d_out, int out_size, void* d_ws, size_t ws_size,
                              hipStream_t stream) {
    const float* t  = (const float*)d_in[0];
    const float* x0 = (const float*)d_in[1];
    const float* W1 = (const float*)d_in[2];
    const float* b1 = (const float*)d_in[3];
    const float* W2 = (const float*)d_in[4];
    const float* b2 = (const float*)d_in[5];
    const float* W3 = (const float*)d_in[6];
    // d_in[7] = b3: additive constant in H, cancels in dH/dx — unused.

    hnn_rk4_kernel<<<dim3(BATCH / 4), dim3(256), 0, stream>>>(
        t, x0, W1, b1, W2, b2, W3, (float*)d_out);
}